// Round 9
// baseline (96.947 us; speedup 1.0000x reference)
//
#include <hip/hip_runtime.h>
#include <hip/hip_bf16.h>

// proto_net_loss, 5 dispatches:
//  prep:   W1T/W2T bf16 transposed weights (tiled, coalesced)
//  gemm1:  H(bf16) = X @ W1; 640 blocks x 4 waves FRAG-SPLIT (wave = 16 rows x 32 cols,
//          full K=512) + per-strip BN partial stats. 2560 waves for TLP.
//  final:  BN scale/shift per set (1 block)
//  gemm2:  Z(bf16) = relu(H*sc+sh) @ W2; 640 blocks frag-split + f32 row norms
//  dist:   D = n1[i]+n2[j]-2*Z1@Z2^T; swapped-operand MFMA, LDS-staged wide stores

#define LAT 512
#define HID 128
#define EPSV 1e-5f

typedef __attribute__((ext_vector_type(8))) short bf16x8;
typedef __attribute__((ext_vector_type(4))) float f32x4;

__device__ __forceinline__ unsigned short f2bf(float x) {  // RTNE
  unsigned int u = __builtin_bit_cast(unsigned int, x);
  return (unsigned short)((u + 0x7fffu + ((u >> 16) & 1u)) >> 16);
}
__device__ __forceinline__ float bf2f(unsigned short h) {
  unsigned int u = ((unsigned int)h) << 16;
  return __builtin_bit_cast(float, u);
}

// ---------------- prep: tiled transpose f32 -> bf16 ----------------
__global__ __launch_bounds__(256) void k_prep(const float* __restrict__ W1,
                                              const float* __restrict__ W2,
                                              unsigned short* __restrict__ W1T,
                                              unsigned short* __restrict__ W2T) {
  __shared__ float T[64][65];
  const int t = threadIdx.x;
  int bi = blockIdx.x;
  const float* src;
  unsigned short* dst;
  int K, N, tk, tn;
  if (bi < 16) { src = W1; dst = W1T; K = LAT; N = HID; tk = bi >> 1; tn = bi & 1; }
  else { bi -= 16; src = W2; dst = W2T; K = HID; N = HID; tk = bi >> 1; tn = bi & 1; }
  const int k0 = tk * 64, n0 = tn * 64;
  {
    const int rr = t >> 4, cc = (t & 15) * 4;
#pragma unroll
    for (int i = 0; i < 4; ++i) {
      const int r = rr + i * 16;
      const float4 v = *(const float4*)(src + (size_t)(k0 + r) * N + n0 + cc);
      T[cc + 0][r] = v.x; T[cc + 1][r] = v.y; T[cc + 2][r] = v.z; T[cc + 3][r] = v.w;
    }
  }
  __syncthreads();
  {
    const int nn = t >> 2, q = (t & 3) * 16;
    unsigned short* dp = dst + (size_t)(n0 + nn) * K + k0 + q;
#pragma unroll
    for (int j = 0; j < 4; ++j) {
      ushort4 o = {f2bf(T[nn][q + j * 4 + 0]), f2bf(T[nn][q + j * 4 + 1]),
                   f2bf(T[nn][q + j * 4 + 2]), f2bf(T[nn][q + j * 4 + 3])};
      *(ushort4*)(dp + j * 4) = o;
    }
  }
}

// ---------------- gemm1: frag-split, wave = 16 rows x 2 frags, K=512 ----------------
__global__ __launch_bounds__(256) void k_gemm1(
    const float* __restrict__ X1, const float* __restrict__ X2, int nx,
    const unsigned short* __restrict__ W1T, unsigned short* __restrict__ H,
    float* __restrict__ pS, float* __restrict__ pQ, int nb1) {
  __shared__ float sS[4][HID], sQ[4][HID];
  const int tid = threadIdx.x, w = tid >> 6, lane = tid & 63;
  const int l15 = lane & 15, lq = lane >> 4, lk8 = lq * 8;
  const int b = (int)blockIdx.x;
  const int row0 = b * 16;
  const bool set1 = b < nb1;
  const float* X = set1 ? X1 : X2;
  const int xrow = set1 ? row0 : row0 - nx;
  const float* xptr = X + (size_t)(xrow + l15) * LAT + lk8;

  f32x4 acc[2];
  acc[0] = (f32x4){0.f, 0.f, 0.f, 0.f};
  acc[1] = (f32x4){0.f, 0.f, 0.f, 0.f};
#pragma unroll
  for (int s = 0; s < 16; ++s) {
    const float4 x0 = *(const float4*)(xptr + s * 32);
    const float4 x1 = *(const float4*)(xptr + s * 32 + 4);
    const float vv[8] = {x0.x, x0.y, x0.z, x0.w, x1.x, x1.y, x1.z, x1.w};
    bf16x8 bfr;
#pragma unroll
    for (int i = 0; i < 8; ++i) bfr[i] = (short)f2bf(vv[i]);
    const int k = s * 32 + lk8;
#pragma unroll
    for (int ff = 0; ff < 2; ++ff) {
      const int f = w * 2 + ff;
      const bf16x8 afr = *(const bf16x8*)(W1T + (size_t)(f * 16 + l15) * LAT + k);
      acc[ff] = __builtin_amdgcn_mfma_f32_16x16x32_bf16(afr, bfr, acc[ff], 0, 0, 0);
    }
  }
  // lane holds H[row0+l15][f*16+lq*4+e]; store + per-strip column stats
#pragma unroll
  for (int ff = 0; ff < 2; ++ff) {
    const int f = w * 2 + ff;
    ushort4 hz = {f2bf(acc[ff][0]), f2bf(acc[ff][1]), f2bf(acc[ff][2]), f2bf(acc[ff][3])};
    *(ushort4*)(H + (size_t)(row0 + l15) * HID + f * 16 + lq * 4) = hz;
    f32x4 s = acc[ff];
    f32x4 q = acc[ff] * acc[ff];
#pragma unroll
    for (int r = 0; r < 4; ++r) {
      s[r] += __shfl_xor(s[r], 1, 64);
      q[r] += __shfl_xor(q[r], 1, 64);
      s[r] += __shfl_xor(s[r], 2, 64);
      q[r] += __shfl_xor(q[r], 2, 64);
    }
    if ((l15 & 3) == 0) {
      *(f32x4*)&sS[l15 >> 2][f * 16 + lq * 4] = s;
      *(f32x4*)&sQ[l15 >> 2][f * 16 + lq * 4] = q;
    }
  }
  __syncthreads();
  if (tid < HID) {
    const float s = sS[0][tid] + sS[1][tid] + sS[2][tid] + sS[3][tid];
    const float q = sQ[0][tid] + sQ[1][tid] + sQ[2][tid] + sQ[3][tid];
    pS[(size_t)b * HID + tid] = s;
    pQ[(size_t)b * HID + tid] = q;
  }
}

// ---------------- finalize BN affine per set (1 block, 256 threads) ----------------
__global__ __launch_bounds__(256) void k_finalize(
    const float* __restrict__ pS, const float* __restrict__ pQ,
    const float* __restrict__ gamma, const float* __restrict__ beta,
    float* __restrict__ sc1, float* __restrict__ sh1,
    float* __restrict__ sc2, float* __restrict__ sh2,
    int nb1, int nblk, float n1c, float n2c) {
  __shared__ f32x4 sA[8][32], qA[8][32], sB[8][32], qB[8][32];
  const int tid = threadIdx.x;
  const int chunk = tid >> 5, cq = tid & 31;
  const int len1 = nb1 >> 3, len2 = (nblk - nb1) >> 3;
  {
    f32x4 s = {0.f, 0.f, 0.f, 0.f}, q = {0.f, 0.f, 0.f, 0.f};
    const int r0 = chunk * len1;
    for (int r = 0; r < len1; ++r) {
      s += *(const f32x4*)(pS + (size_t)(r0 + r) * HID + cq * 4);
      q += *(const f32x4*)(pQ + (size_t)(r0 + r) * HID + cq * 4);
    }
    sA[chunk][cq] = s; qA[chunk][cq] = q;
  }
  {
    f32x4 s = {0.f, 0.f, 0.f, 0.f}, q = {0.f, 0.f, 0.f, 0.f};
    const int r0 = nb1 + chunk * len2;
    for (int r = 0; r < len2; ++r) {
      s += *(const f32x4*)(pS + (size_t)(r0 + r) * HID + cq * 4);
      q += *(const f32x4*)(pQ + (size_t)(r0 + r) * HID + cq * 4);
    }
    sB[chunk][cq] = s; qB[chunk][cq] = q;
  }
  __syncthreads();
  if (tid < 64) {
    const int set = tid >> 5, c = tid & 31;
    f32x4 s = {0.f, 0.f, 0.f, 0.f}, q = {0.f, 0.f, 0.f, 0.f};
#pragma unroll
    for (int ch = 0; ch < 8; ++ch) {
      s += set ? sB[ch][c] : sA[ch][c];
      q += set ? qB[ch][c] : qA[ch][c];
    }
    const float n = set ? n2c : n1c;
    float* sc = set ? sc2 : sc1;
    float* sh = set ? sh2 : sh1;
#pragma unroll
    for (int e = 0; e < 4; ++e) {
      const int col = c * 4 + e;
      const float mean = s[e] / n;
      const float var = q[e] / n - mean * mean;
      const float rstd = rsqrtf(var + EPSV);
      const float scale = gamma[col] * rstd;
      const float shift = beta[col] - mean * scale;
      sc[col] = scale;
      sh[col] = shift;
    }
  }
}

// ---------------- gemm2: frag-split, Z(bf16) + f32 row norms ----------------
__global__ __launch_bounds__(256) void k_gemm2(
    const unsigned short* __restrict__ H, int nx,
    const unsigned short* __restrict__ W2T,
    const float* __restrict__ sc1, const float* __restrict__ sh1,
    const float* __restrict__ sc2, const float* __restrict__ sh2,
    unsigned short* __restrict__ Z, float* __restrict__ nrm) {
  __shared__ float sN[4][16];
  const int tid = threadIdx.x, w = tid >> 6, lane = tid & 63;
  const int l15 = lane & 15, lq = lane >> 4, lk8 = lq * 8;
  const int row0 = (int)blockIdx.x * 16;
  const bool set1 = row0 < nx;
  const float* sc = set1 ? sc1 : sc2;
  const float* sh = set1 ? sh1 : sh2;
  const unsigned short* hptr = H + (size_t)(row0 + l15) * HID + lk8;
  f32x4 acc[2];
  acc[0] = (f32x4){0.f, 0.f, 0.f, 0.f};
  acc[1] = (f32x4){0.f, 0.f, 0.f, 0.f};
#pragma unroll
  for (int s = 0; s < 4; ++s) {
    const int k = s * 32 + lk8;
    const bf16x8 hv = *(const bf16x8*)(hptr + s * 32);
    const float4 c0 = *(const float4*)(sc + k);
    const float4 c1 = *(const float4*)(sc + k + 4);
    const float4 d0 = *(const float4*)(sh + k);
    const float4 d1 = *(const float4*)(sh + k + 4);
    const float ccv[8] = {c0.x, c0.y, c0.z, c0.w, c1.x, c1.y, c1.z, c1.w};
    const float ddv[8] = {d0.x, d0.y, d0.z, d0.w, d1.x, d1.y, d1.z, d1.w};
    bf16x8 bfr;
#pragma unroll
    for (int i = 0; i < 8; ++i) {
      const float a = fmaxf(fmaf(bf2f((unsigned short)hv[i]), ccv[i], ddv[i]), 0.f);
      bfr[i] = (short)f2bf(a);
    }
#pragma unroll
    for (int ff = 0; ff < 2; ++ff) {
      const int f = w * 2 + ff;
      const bf16x8 afr = *(const bf16x8*)(W2T + (size_t)(f * 16 + l15) * HID + k);
      acc[ff] = __builtin_amdgcn_mfma_f32_16x16x32_bf16(afr, bfr, acc[ff], 0, 0, 0);
    }
  }
  float rn = 0.f;
#pragma unroll
  for (int ff = 0; ff < 2; ++ff) {
    rn += acc[ff][0] * acc[ff][0] + acc[ff][1] * acc[ff][1] +
          acc[ff][2] * acc[ff][2] + acc[ff][3] * acc[ff][3];
    const int f = w * 2 + ff;
    ushort4 z4 = {f2bf(acc[ff][0]), f2bf(acc[ff][1]), f2bf(acc[ff][2]), f2bf(acc[ff][3])};
    *(ushort4*)(Z + (size_t)(row0 + l15) * HID + f * 16 + lq * 4) = z4;
  }
  rn += __shfl_xor(rn, 16, 64);
  rn += __shfl_xor(rn, 32, 64);
  if (lane < 16) sN[w][l15] = rn;
  __syncthreads();
  if (w == 0 && lane < 16)
    nrm[row0 + l15] = sN[0][l15] + sN[1][l15] + sN[2][l15] + sN[3][l15];
}

// ---------------- dist: D = n1[i]+n2[j]-2*Z1@Z2^T, LDS-staged wide-segment stores ----
__global__ __launch_bounds__(256) void k_dist(const unsigned short* __restrict__ Z1b,
                                              const unsigned short* __restrict__ Z2b,
                                              const float* __restrict__ n1,
                                              const float* __restrict__ n2,
                                              float* __restrict__ D, int NY) {
  __shared__ float lds[4][16][68];
  const int tid = threadIdx.x;
  const int wid = tid >> 6, lane = tid & 63;
  const int wr = wid >> 1, wc = wid & 1;
  const int rowB = blockIdx.y * 128 + wr * 64;
  const int colB = blockIdx.x * 128 + wc * 64;
  const int l15 = lane & 15, lq = lane >> 4;
  const int lk = lq * 8;
  const unsigned short* Arow = Z1b + (size_t)(rowB + l15) * HID + lk;
  const unsigned short* Brow = Z2b + (size_t)(colB + l15) * HID + lk;
  f32x4 acc[4][4];
#pragma unroll
  for (int i = 0; i < 4; ++i)
#pragma unroll
    for (int j = 0; j < 4; ++j) acc[i][j] = (f32x4){0.f, 0.f, 0.f, 0.f};
#pragma unroll
  for (int s = 0; s < 4; ++s) {
    bf16x8 a[4], b[4];
#pragma unroll
    for (int i = 0; i < 4; ++i) a[i] = *(const bf16x8*)(Arow + (size_t)i * 16 * HID + s * 32);
#pragma unroll
    for (int j = 0; j < 4; ++j) b[j] = *(const bf16x8*)(Brow + (size_t)j * 16 * HID + s * 32);
#pragma unroll
    for (int i = 0; i < 4; ++i)
#pragma unroll
      for (int j = 0; j < 4; ++j)
        acc[i][j] = __builtin_amdgcn_mfma_f32_16x16x32_bf16(b[j], a[i], acc[i][j], 0, 0, 0);
  }
  const int cq = lq * 4;
  float na[4];
#pragma unroll
  for (int i = 0; i < 4; ++i) na[i] = n1[rowB + i * 16 + l15];
  const int h = lane >> 4;
  const int cl = (lane & 15) << 2;
#pragma unroll
  for (int i = 0; i < 4; ++i) {
#pragma unroll
    for (int j = 0; j < 4; ++j) {
      const float4 nbv = *(const float4*)(n2 + colB + j * 16 + cq);
      f32x4 ov;
      ov[0] = na[i] + nbv.x - 2.f * acc[i][j][0];
      ov[1] = na[i] + nbv.y - 2.f * acc[i][j][1];
      ov[2] = na[i] + nbv.z - 2.f * acc[i][j][2];
      ov[3] = na[i] + nbv.w - 2.f * acc[i][j][3];
      *(f32x4*)&lds[wid][l15][j * 16 + cq] = ov;
    }
    __syncthreads();
    float* dbase = D + (size_t)(rowB + i * 16) * NY + colB;
#pragma unroll
    for (int rr = 0; rr < 4; ++rr) {
      const int r = (rr << 2) + h;
      const f32x4 v = *(const f32x4*)&lds[wid][r][cl];
      *(f32x4*)(dbase + (size_t)r * NY + cl) = v;
    }
    __syncthreads();
  }
}

extern "C" void kernel_launch(void* const* d_in, const int* in_sizes, int n_in,
                              void* d_out, int out_size, void* d_ws, size_t ws_size,
                              hipStream_t stream) {
  const float* variations = (const float*)d_in[0];
  const float* exemplar   = (const float*)d_in[1];
  const float* w1         = (const float*)d_in[2];
  const float* gamma      = (const float*)d_in[3];
  const float* beta       = (const float*)d_in[4];
  const float* w2         = (const float*)d_in[5];
  float* D = (float*)d_out;

  const int nx = in_sizes[0] / LAT;  // 8192
  const int ny = in_sizes[1] / LAT;  // 2048
  const int nrows = nx + ny;         // 10240
  const int nblk = nrows / 16;       // 640 strip blocks
  const int nb1 = nx / 16;           // 512

  char* p = (char*)d_ws;
  unsigned short* Hb  = (unsigned short*)p; p += (size_t)nrows * HID * 2;
  unsigned short* Zb  = (unsigned short*)p; p += (size_t)nrows * HID * 2;
  unsigned short* W1T = (unsigned short*)p; p += (size_t)LAT * HID * 2;
  unsigned short* W2T = (unsigned short*)p; p += (size_t)HID * HID * 2;
  float* pS = (float*)p;  p += (size_t)nblk * HID * 4;
  float* pQ = (float*)p;  p += (size_t)nblk * HID * 4;
  float* sc1 = (float*)p; p += HID * 4;
  float* sh1 = (float*)p; p += HID * 4;
  float* sc2 = (float*)p; p += HID * 4;
  float* sh2 = (float*)p; p += HID * 4;
  float* nrmAll = (float*)p; p += (size_t)nrows * 4;
  float* n1v = nrmAll;
  float* n2v = nrmAll + nx;
  unsigned short* Z1b = Zb;
  unsigned short* Z2b = Zb + (size_t)nx * HID;

  k_prep<<<20, 256, 0, stream>>>(w1, w2, W1T, W2T);
  k_gemm1<<<nblk, 256, 0, stream>>>(variations, exemplar, nx, W1T, Hb, pS, pQ, nb1);
  k_finalize<<<1, 256, 0, stream>>>(pS, pQ, gamma, beta, sc1, sh1, sc2, sh2,
                                    nb1, nblk, (float)nx, (float)ny);
  k_gemm2<<<nblk, 256, 0, stream>>>(Hb, nx, W2T, sc1, sh1, sc2, sh2, Zb, nrmAll);
  dim3 dgrid(ny / 128, nx / 128);
  k_dist<<<dgrid, 256, 0, stream>>>(Z1b, Z2b, n1v, n2v, D, ny);
}

// Round 10
// 76.808 us; speedup vs baseline: 1.2622x; 1.2622x over previous
//
#include <hip/hip_runtime.h>
#include <hip/hip_bf16.h>

// proto_net_loss, 5 dispatches — round-3 anchor + improved dist:
//  prep:   W1T/W2T = bf16 transposed weights (L2-resident)
//  gemm1:  H(bf16) = X @ W1 via MFMA (160 blocks x 4 waves, wave = 16 rows x 128 cols,
//          full K=512), fused per-block BN partial stats
//  final:  BN scale/shift per set
//  gemm2:  Z(bf16) = relu(H*sc+sh) @ W2 + f32 row norms (160 blocks, 8 frags/wave)
//  dist:   D = n1[i]+n2[j]-2*Z1@Z2^T; swapped-operand MFMA -> float4 stores;
//          XCD-swizzled tile index for per-XCD L2 locality

#define LAT 512
#define HID 128
#define EPSV 1e-5f

typedef __attribute__((ext_vector_type(8))) short bf16x8;
typedef __attribute__((ext_vector_type(4))) float f32x4;

__device__ __forceinline__ unsigned short f2bf(float x) {  // RTNE
  unsigned int u = __builtin_bit_cast(unsigned int, x);
  return (unsigned short)((u + 0x7fffu + ((u >> 16) & 1u)) >> 16);
}
__device__ __forceinline__ float bf2f(unsigned short h) {
  unsigned int u = ((unsigned int)h) << 16;
  return __builtin_bit_cast(float, u);
}

// ---------------- prep: transpose weights to bf16 (tiled, coalesced) ----------------
__global__ __launch_bounds__(256) void k_prep(const float* __restrict__ W1,
                                              const float* __restrict__ W2,
                                              unsigned short* __restrict__ W1T,
                                              unsigned short* __restrict__ W2T) {
  __shared__ float T[64][65];
  const int t = threadIdx.x;
  int bi = blockIdx.x;
  const float* src;
  unsigned short* dst;
  int K, N, tk, tn;
  if (bi < 16) { src = W1; dst = W1T; K = LAT; N = HID; tk = bi >> 1; tn = bi & 1; }
  else { bi -= 16; src = W2; dst = W2T; K = HID; N = HID; tk = bi >> 1; tn = bi & 1; }
  const int k0 = tk * 64, n0 = tn * 64;
  {
    const int rr = t >> 4, cc = (t & 15) * 4;
#pragma unroll
    for (int i = 0; i < 4; ++i) {
      const int r = rr + i * 16;
      const float4 v = *(const float4*)(src + (size_t)(k0 + r) * N + n0 + cc);
      T[cc + 0][r] = v.x; T[cc + 1][r] = v.y; T[cc + 2][r] = v.z; T[cc + 3][r] = v.w;
    }
  }
  __syncthreads();
  {
    const int nn = t >> 2, q = (t & 3) * 16;
    unsigned short* dp = dst + (size_t)(n0 + nn) * K + k0 + q;
#pragma unroll
    for (int j = 0; j < 4; ++j) {
      ushort4 o = {f2bf(T[nn][q + j * 4 + 0]), f2bf(T[nn][q + j * 4 + 1]),
                   f2bf(T[nn][q + j * 4 + 2]), f2bf(T[nn][q + j * 4 + 3])};
      *(ushort4*)(dp + j * 4) = o;
    }
  }
}

// ---------------- gemm1: H = X @ W1 (MFMA) + partial stats (round-3 shape) ----------------
// 4 waves/block, each wave: 16 rows x 128 cols, K=512. grid = 160.
__global__ __launch_bounds__(256) void k_gemm1(
    const float* __restrict__ X1, const float* __restrict__ X2, int nx,
    const unsigned short* __restrict__ W1T, unsigned short* __restrict__ H,
    float* __restrict__ pS1, float* __restrict__ pQ1,
    float* __restrict__ pS2, float* __restrict__ pQ2, int nb1) {
  __shared__ float sS[16][HID], sQ[16][HID];
  const int tid = threadIdx.x, wid = tid >> 6, lane = tid & 63;
  const int l15 = lane & 15, lq = lane >> 4, lk8 = lq * 8;
  const int browBase = (int)blockIdx.x * 64;
  const int row0 = browBase + wid * 16;
  const float* X = (browBase < nx) ? X1 : X2;
  const int xrow = (browBase < nx) ? row0 : row0 - nx;
  const float* xptr = X + (size_t)(xrow + l15) * LAT + lk8;
  f32x4 acc[8];
#pragma unroll
  for (int f = 0; f < 8; ++f) acc[f] = (f32x4){0.f, 0.f, 0.f, 0.f};

#pragma unroll
  for (int kb = 0; kb < LAT; kb += 128) {
    float4 xv[4][2];
#pragma unroll
    for (int s = 0; s < 4; ++s) {
      xv[s][0] = *(const float4*)(xptr + kb + s * 32);
      xv[s][1] = *(const float4*)(xptr + kb + s * 32 + 4);
    }
#pragma unroll
    for (int s = 0; s < 4; ++s) {
      const float vv[8] = {xv[s][0].x, xv[s][0].y, xv[s][0].z, xv[s][0].w,
                           xv[s][1].x, xv[s][1].y, xv[s][1].z, xv[s][1].w};
      bf16x8 bfr;
#pragma unroll
      for (int i = 0; i < 8; ++i) bfr[i] = (short)f2bf(vv[i]);
      const int k = kb + s * 32 + lk8;
#pragma unroll
      for (int f = 0; f < 8; ++f) {
        const bf16x8 afr = *(const bf16x8*)(W1T + (size_t)(f * 16 + l15) * LAT + k);
        acc[f] = __builtin_amdgcn_mfma_f32_16x16x32_bf16(afr, bfr, acc[f], 0, 0, 0);
      }
    }
  }
  // store H row-major bf16: lane holds H[m=row0+l15][n=f*16+lq*4+r]
#pragma unroll
  for (int f = 0; f < 8; ++f) {
    ushort4 hz = {f2bf(acc[f][0]), f2bf(acc[f][1]), f2bf(acc[f][2]), f2bf(acc[f][3])};
    *(ushort4*)(H + (size_t)(row0 + l15) * HID + f * 16 + lq * 4) = hz;
  }
  // partial stats: 2 shfl stages then LDS fold
#pragma unroll
  for (int f = 0; f < 8; ++f) {
    f32x4 s = acc[f];
    f32x4 q = acc[f] * acc[f];
#pragma unroll
    for (int r = 0; r < 4; ++r) {
      s[r] += __shfl_xor(s[r], 1, 64);
      q[r] += __shfl_xor(q[r], 1, 64);
      s[r] += __shfl_xor(s[r], 2, 64);
      q[r] += __shfl_xor(q[r], 2, 64);
    }
    if ((l15 & 3) == 0) {
      *(f32x4*)&sS[wid * 4 + (l15 >> 2)][f * 16 + lq * 4] = s;
      *(f32x4*)&sQ[wid * 4 + (l15 >> 2)][f * 16 + lq * 4] = q;
    }
  }
  __syncthreads();
  if (tid < HID) {
    float s = 0.f, q = 0.f;
#pragma unroll
    for (int r = 0; r < 16; ++r) { s += sS[r][tid]; q += sQ[r][tid]; }
    float* pS = (blockIdx.x < (unsigned)nb1) ? pS1 + (size_t)blockIdx.x * HID
                                             : pS2 + (size_t)(blockIdx.x - nb1) * HID;
    float* pQ = (blockIdx.x < (unsigned)nb1) ? pQ1 + (size_t)blockIdx.x * HID
                                             : pQ2 + (size_t)(blockIdx.x - nb1) * HID;
    pS[tid] = s;
    pQ[tid] = q;
  }
}

// ---------------- finalize BN affine per set ----------------
__global__ __launch_bounds__(1024) void k_finalize(
    const float* __restrict__ pS1, const float* __restrict__ pQ1,
    const float* __restrict__ pS2, const float* __restrict__ pQ2,
    const float* __restrict__ gamma, const float* __restrict__ beta,
    float* __restrict__ sc1, float* __restrict__ sh1,
    float* __restrict__ sc2, float* __restrict__ sh2,
    int nb1, int nb2, float n1count, float n2count) {
  __shared__ float sA[8][HID], qA[8][HID], sB[2][HID], qB[2][HID];
  const int tid = threadIdx.x;
  const int col = tid & 127, chunk = tid >> 7;  // 0..7
  {
    const int len = nb1 >> 3;  // 16
    const int b0 = chunk * len;
    float s = 0.f, q = 0.f;
    for (int b = b0; b < b0 + len; ++b) {
      s += pS1[(size_t)b * HID + col];
      q += pQ1[(size_t)b * HID + col];
    }
    sA[chunk][col] = s;
    qA[chunk][col] = q;
  }
  if (chunk < 2) {
    const int len = nb2 >> 1;  // 16
    const int b0 = chunk * len;
    float s = 0.f, q = 0.f;
    for (int b = b0; b < b0 + len; ++b) {
      s += pS2[(size_t)b * HID + col];
      q += pQ2[(size_t)b * HID + col];
    }
    sB[chunk][col] = s;
    qB[chunk][col] = q;
  }
  __syncthreads();
  if (tid < 256) {
    const int c = tid & 127;
    const bool one = tid < 128;
    float s = 0.f, q = 0.f;
    if (one) {
#pragma unroll
      for (int r = 0; r < 8; ++r) { s += sA[r][c]; q += qA[r][c]; }
    } else {
      s = sB[0][c] + sB[1][c];
      q = qB[0][c] + qB[1][c];
    }
    const float n = one ? n1count : n2count;
    const float mean = s / n;
    const float var = q / n - mean * mean;
    const float rstd = rsqrtf(var + EPSV);
    const float scale = gamma[c] * rstd;
    const float shift = beta[c] - mean * scale;
    if (one) { sc1[c] = scale; sh1[c] = shift; }
    else     { sc2[c] = scale; sh2[c] = shift; }
  }
}

// ---------------- gemm2: Z(bf16) = relu(H*sc+sh) @ W2 + f32 row norms ----------------
__global__ __launch_bounds__(256) void k_gemm2(
    const unsigned short* __restrict__ H, int nx,
    const unsigned short* __restrict__ W2T,
    const float* __restrict__ sc1, const float* __restrict__ sh1,
    const float* __restrict__ sc2, const float* __restrict__ sh2,
    unsigned short* __restrict__ Z, float* __restrict__ nrm) {
  const int tid = threadIdx.x, wid = tid >> 6, lane = tid & 63;
  const int l15 = lane & 15, lq = lane >> 4, lk8 = lq * 8;
  const int row0 = (int)blockIdx.x * 64 + wid * 16;
  const bool set1 = row0 < nx;
  const float* sc = set1 ? sc1 : sc2;
  const float* sh = set1 ? sh1 : sh2;
  const unsigned short* hptr = H + (size_t)(row0 + l15) * HID + lk8;
  f32x4 acc[8];
#pragma unroll
  for (int f = 0; f < 8; ++f) acc[f] = (f32x4){0.f, 0.f, 0.f, 0.f};
#pragma unroll
  for (int s = 0; s < 4; ++s) {
    const int k = s * 32 + lk8;
    const bf16x8 hv = *(const bf16x8*)(hptr + s * 32);
    const float4 c0 = *(const float4*)(sc + k);
    const float4 c1 = *(const float4*)(sc + k + 4);
    const float4 d0 = *(const float4*)(sh + k);
    const float4 d1 = *(const float4*)(sh + k + 4);
    const float cc[8] = {c0.x, c0.y, c0.z, c0.w, c1.x, c1.y, c1.z, c1.w};
    const float dd[8] = {d0.x, d0.y, d0.z, d0.w, d1.x, d1.y, d1.z, d1.w};
    bf16x8 bfr;
#pragma unroll
    for (int i = 0; i < 8; ++i) {
      const float a = fmaxf(fmaf(bf2f((unsigned short)hv[i]), cc[i], dd[i]), 0.f);
      bfr[i] = (short)f2bf(a);
    }
#pragma unroll
    for (int f = 0; f < 8; ++f) {
      const bf16x8 afr = *(const bf16x8*)(W2T + (size_t)(f * 16 + l15) * HID + k);
      acc[f] = __builtin_amdgcn_mfma_f32_16x16x32_bf16(afr, bfr, acc[f], 0, 0, 0);
    }
  }
  float rn = 0.f;
#pragma unroll
  for (int f = 0; f < 8; ++f) {
    rn += acc[f][0] * acc[f][0] + acc[f][1] * acc[f][1] +
          acc[f][2] * acc[f][2] + acc[f][3] * acc[f][3];
    ushort4 z4 = {f2bf(acc[f][0]), f2bf(acc[f][1]), f2bf(acc[f][2]), f2bf(acc[f][3])};
    *(ushort4*)(Z + (size_t)(row0 + l15) * HID + f * 16 + lq * 4) = z4;
  }
  rn += __shfl_xor(rn, 16, 64);
  rn += __shfl_xor(rn, 32, 64);
  if (lane < 16) nrm[row0 + l15] = rn;
}

// ---------------- dist: D = n1[i]+n2[j]-2*Z1@Z2^T, float4 stores, XCD swizzle ----------
__global__ __launch_bounds__(256) void k_dist(const unsigned short* __restrict__ Z1b,
                                              const unsigned short* __restrict__ Z2b,
                                              const float* __restrict__ n1,
                                              const float* __restrict__ n2,
                                              float* __restrict__ D, int NY, int ntx) {
  // bijective XCD swizzle (nwg % 8 == 0): each XCD gets a contiguous chunk of tiles
  const int nwg = (int)gridDim.x;
  const int cpx = nwg >> 3;
  const int bid = (int)blockIdx.x;
  const int wgid = (bid & 7) * cpx + (bid >> 3);
  const int tby = wgid / ntx, tbx = wgid - tby * ntx;

  const int tid = threadIdx.x;
  const int wid = tid >> 6, lane = tid & 63;
  const int wr = wid >> 1, wc = wid & 1;
  const int rowB = tby * 128 + wr * 64;
  const int colB = tbx * 128 + wc * 64;
  const int l15 = lane & 15, lq = lane >> 4;
  const int lk = lq * 8;
  const unsigned short* Arow = Z1b + (size_t)(rowB + l15) * HID + lk;
  const unsigned short* Brow = Z2b + (size_t)(colB + l15) * HID + lk;
  f32x4 acc[4][4];
#pragma unroll
  for (int i = 0; i < 4; ++i)
#pragma unroll
    for (int j = 0; j < 4; ++j) acc[i][j] = (f32x4){0.f, 0.f, 0.f, 0.f};
#pragma unroll
  for (int s = 0; s < 4; ++s) {
    bf16x8 a[4], b[4];
#pragma unroll
    for (int i = 0; i < 4; ++i) a[i] = *(const bf16x8*)(Arow + (size_t)i * 16 * HID + s * 32);
#pragma unroll
    for (int j = 0; j < 4; ++j) b[j] = *(const bf16x8*)(Brow + (size_t)j * 16 * HID + s * 32);
#pragma unroll
    for (int i = 0; i < 4; ++i)
#pragma unroll
      for (int j = 0; j < 4; ++j)
        acc[i][j] = __builtin_amdgcn_mfma_f32_16x16x32_bf16(b[j], a[i], acc[i][j], 0, 0, 0);
  }
  // lane holds D[rowB + i*16 + l15][colB + j*16 + lq*4 + r], r=0..3
  const int cq = lq * 4;
  float na[4];
#pragma unroll
  for (int i = 0; i < 4; ++i) na[i] = n1[rowB + i * 16 + l15];
#pragma unroll
  for (int j = 0; j < 4; ++j) {
    const float4 nbv = *(const float4*)(n2 + colB + j * 16 + cq);
#pragma unroll
    for (int i = 0; i < 4; ++i) {
      float4 o;
      o.x = na[i] + nbv.x - 2.f * acc[i][j][0];
      o.y = na[i] + nbv.y - 2.f * acc[i][j][1];
      o.z = na[i] + nbv.z - 2.f * acc[i][j][2];
      o.w = na[i] + nbv.w - 2.f * acc[i][j][3];
      *(float4*)(D + (size_t)(rowB + i * 16 + l15) * NY + colB + j * 16 + cq) = o;
    }
  }
}

extern "C" void kernel_launch(void* const* d_in, const int* in_sizes, int n_in,
                              void* d_out, int out_size, void* d_ws, size_t ws_size,
                              hipStream_t stream) {
  const float* variations = (const float*)d_in[0];
  const float* exemplar   = (const float*)d_in[1];
  const float* w1         = (const float*)d_in[2];
  const float* gamma      = (const float*)d_in[3];
  const float* beta       = (const float*)d_in[4];
  const float* w2         = (const float*)d_in[5];
  float* D = (float*)d_out;

  const int nx = in_sizes[0] / LAT;  // 8192
  const int ny = in_sizes[1] / LAT;  // 2048
  const int nrows = nx + ny;         // 10240
  const int nbb = nrows / 64;        // 160
  const int nb1 = nx / 64;           // 128
  const int nb2 = ny / 64;           // 32

  char* p = (char*)d_ws;
  unsigned short* Hb  = (unsigned short*)p; p += (size_t)nrows * HID * 2;
  unsigned short* Zb  = (unsigned short*)p; p += (size_t)nrows * HID * 2;
  unsigned short* W1T = (unsigned short*)p; p += (size_t)LAT * HID * 2;
  unsigned short* W2T = (unsigned short*)p; p += (size_t)HID * HID * 2;
  float* pS1 = (float*)p; p += (size_t)nb1 * HID * 4;
  float* pQ1 = (float*)p; p += (size_t)nb1 * HID * 4;
  float* pS2 = (float*)p; p += (size_t)nb2 * HID * 4;
  float* pQ2 = (float*)p; p += (size_t)nb2 * HID * 4;
  float* sc1 = (float*)p; p += HID * 4;
  float* sh1 = (float*)p; p += HID * 4;
  float* sc2 = (float*)p; p += HID * 4;
  float* sh2 = (float*)p; p += HID * 4;
  float* nrmAll = (float*)p; p += (size_t)nrows * 4;
  float* n1v = nrmAll;
  float* n2v = nrmAll + nx;
  unsigned short* Z1b = Zb;
  unsigned short* Z2b = Zb + (size_t)nx * HID;

  k_prep<<<20, 256, 0, stream>>>(w1, w2, W1T, W2T);
  k_gemm1<<<nbb, 256, 0, stream>>>(variations, exemplar, nx, W1T, Hb,
                                   pS1, pQ1, pS2, pQ2, nb1);
  k_finalize<<<1, 1024, 0, stream>>>(pS1, pQ1, pS2, pQ2, gamma, beta,
                                     sc1, sh1, sc2, sh2, nb1, nb2, (float)nx, (float)ny);
  k_gemm2<<<nbb, 256, 0, stream>>>(Hb, nx, W2T, sc1, sh1, sc2, sh2, Zb, nrmAll);
  const int ntx = ny / 128;                  // 16
  const int nwg = (nx / 128) * ntx;          // 1024
  k_dist<<<nwg, 256, 0, stream>>>(Z1b, Z2b, n1v, n2v, D, ny, ntx);
}

// Round 11
// 67.724 us; speedup vs baseline: 1.4315x; 1.1341x over previous
//
#include <hip/hip_runtime.h>
#include <hip/hip_bf16.h>

// proto_net_loss, 4 dispatches:
//  prep:   W1T/W2T bf16 transposed weights (20 tile blocks) + X->bf16 conversion
//          (2560 blocks, fused: no extra dispatch)
//  gemm1:  H(bf16) = Xb @ W1 via MFMA (160 blocks x 4 waves, wave = 16 rows x 128 cols,
//          K=512, pure-bf16 fragment loads) + fused per-block BN partial stats
//  gemm2:  [finalize fused in head] Z(bf16) = relu(H*sc+sh) @ W2 + f32 row norms
//  dist:   D = n1[i]+n2[j]-2*Z1@Z2^T; swapped-operand MFMA, float4 stores, XCD swizzle

#define LAT 512
#define HID 128
#define EPSV 1e-5f

typedef __attribute__((ext_vector_type(8))) short bf16x8;
typedef __attribute__((ext_vector_type(4))) float f32x4;

__device__ __forceinline__ unsigned short f2bf(float x) {  // RTNE
  unsigned int u = __builtin_bit_cast(unsigned int, x);
  return (unsigned short)((u + 0x7fffu + ((u >> 16) & 1u)) >> 16);
}
__device__ __forceinline__ float bf2f(unsigned short h) {
  unsigned int u = ((unsigned int)h) << 16;
  return __builtin_bit_cast(float, u);
}

// ---------------- prep: weight transpose tiles + X bf16 conversion ----------------
// blocks 0..15: W1 tiles; 16..19: W2 tiles; 20..: X conversion (2048 elems/block)
__global__ __launch_bounds__(256) void k_prep(const float* __restrict__ W1,
                                              const float* __restrict__ W2,
                                              const float* __restrict__ X1,
                                              const float* __restrict__ X2, int nx,
                                              unsigned short* __restrict__ W1T,
                                              unsigned short* __restrict__ W2T,
                                              unsigned short* __restrict__ Xb) {
  __shared__ float T[64][65];
  const int t = threadIdx.x;
  int bi = blockIdx.x;
  if (bi >= 20) {
    // X conversion: coalesced float4x2 -> ushort4x2
    const size_t base = (size_t)(bi - 20) * 2048 + (size_t)t * 8;
    const size_t nxe = (size_t)nx * LAT;
    const float* src = (base < nxe) ? (X1 + base) : (X2 + (base - nxe));
    const float4 a = *(const float4*)src;
    const float4 b = *(const float4*)(src + 4);
    const ushort4 o0 = {f2bf(a.x), f2bf(a.y), f2bf(a.z), f2bf(a.w)};
    const ushort4 o1 = {f2bf(b.x), f2bf(b.y), f2bf(b.z), f2bf(b.w)};
    *(ushort4*)(Xb + base) = o0;
    *(ushort4*)(Xb + base + 4) = o1;
    return;
  }
  const float* src;
  unsigned short* dst;
  int K, N, tk, tn;
  if (bi < 16) { src = W1; dst = W1T; K = LAT; N = HID; tk = bi >> 1; tn = bi & 1; }
  else { bi -= 16; src = W2; dst = W2T; K = HID; N = HID; tk = bi >> 1; tn = bi & 1; }
  const int k0 = tk * 64, n0 = tn * 64;
  {
    const int rr = t >> 4, cc = (t & 15) * 4;
#pragma unroll
    for (int i = 0; i < 4; ++i) {
      const int r = rr + i * 16;
      const float4 v = *(const float4*)(src + (size_t)(k0 + r) * N + n0 + cc);
      T[cc + 0][r] = v.x; T[cc + 1][r] = v.y; T[cc + 2][r] = v.z; T[cc + 3][r] = v.w;
    }
  }
  __syncthreads();
  {
    const int nn = t >> 2, q = (t & 3) * 16;
    unsigned short* dp = dst + (size_t)(n0 + nn) * K + k0 + q;
#pragma unroll
    for (int j = 0; j < 4; ++j) {
      ushort4 o = {f2bf(T[nn][q + j * 4 + 0]), f2bf(T[nn][q + j * 4 + 1]),
                   f2bf(T[nn][q + j * 4 + 2]), f2bf(T[nn][q + j * 4 + 3])};
      *(ushort4*)(dp + j * 4) = o;
    }
  }
}

// ---------------- gemm1: H = Xb @ W1 (pure bf16 MFMA) + partial stats ----------------
// 4 waves/block, wave = 16 rows x 128 cols, K=512. grid = 160.
__global__ __launch_bounds__(256) void k_gemm1(
    const unsigned short* __restrict__ Xb,
    const unsigned short* __restrict__ W1T, unsigned short* __restrict__ H,
    float* __restrict__ pS, float* __restrict__ pQ) {
  __shared__ float sS[16][HID], sQ[16][HID];
  const int tid = threadIdx.x, wid = tid >> 6, lane = tid & 63;
  const int l15 = lane & 15, lq = lane >> 4, lk8 = lq * 8;
  const int row0 = (int)blockIdx.x * 64 + wid * 16;
  const unsigned short* xptr = Xb + (size_t)(row0 + l15) * LAT + lk8;
  f32x4 acc[8];
#pragma unroll
  for (int f = 0; f < 8; ++f) acc[f] = (f32x4){0.f, 0.f, 0.f, 0.f};

#pragma unroll
  for (int kb = 0; kb < LAT; kb += 128) {
    bf16x8 xv[4];
#pragma unroll
    for (int s = 0; s < 4; ++s) xv[s] = *(const bf16x8*)(xptr + kb + s * 32);
#pragma unroll
    for (int s = 0; s < 4; ++s) {
      const int k = kb + s * 32 + lk8;
#pragma unroll
      for (int f = 0; f < 8; ++f) {
        const bf16x8 afr = *(const bf16x8*)(W1T + (size_t)(f * 16 + l15) * LAT + k);
        acc[f] = __builtin_amdgcn_mfma_f32_16x16x32_bf16(afr, xv[s], acc[f], 0, 0, 0);
      }
    }
  }
  // store H row-major bf16: lane holds H[m=row0+l15][n=f*16+lq*4+r]
#pragma unroll
  for (int f = 0; f < 8; ++f) {
    ushort4 hz = {f2bf(acc[f][0]), f2bf(acc[f][1]), f2bf(acc[f][2]), f2bf(acc[f][3])};
    *(ushort4*)(H + (size_t)(row0 + l15) * HID + f * 16 + lq * 4) = hz;
  }
  // partial stats: 2 shfl stages then LDS fold
#pragma unroll
  for (int f = 0; f < 8; ++f) {
    f32x4 s = acc[f];
    f32x4 q = acc[f] * acc[f];
#pragma unroll
    for (int r = 0; r < 4; ++r) {
      s[r] += __shfl_xor(s[r], 1, 64);
      q[r] += __shfl_xor(q[r], 1, 64);
      s[r] += __shfl_xor(s[r], 2, 64);
      q[r] += __shfl_xor(q[r], 2, 64);
    }
    if ((l15 & 3) == 0) {
      *(f32x4*)&sS[wid * 4 + (l15 >> 2)][f * 16 + lq * 4] = s;
      *(f32x4*)&sQ[wid * 4 + (l15 >> 2)][f * 16 + lq * 4] = q;
    }
  }
  __syncthreads();
  if (tid < HID) {
    float s = 0.f, q = 0.f;
#pragma unroll
    for (int r = 0; r < 16; ++r) { s += sS[r][tid]; q += sQ[r][tid]; }
    pS[(size_t)blockIdx.x * HID + tid] = s;
    pQ[(size_t)blockIdx.x * HID + tid] = q;
  }
}

// ---------------- gemm2: finalize-in-head + Z(bf16) = relu(H*sc+sh)@W2 + row norms ----
__global__ __launch_bounds__(256) void k_gemm2(
    const unsigned short* __restrict__ H,
    const unsigned short* __restrict__ W2T,
    const float* __restrict__ pS, const float* __restrict__ pQ,
    const float* __restrict__ gamma, const float* __restrict__ beta,
    unsigned short* __restrict__ Z, float* __restrict__ nrm,
    int nb1, int nblk, float n1c, float n2c) {
  __shared__ float s_sc[HID], s_sh[HID];
  __shared__ float t0[2][HID], t1[2][HID];
  const int tid = threadIdx.x, wid = tid >> 6, lane = tid & 63;
  const int l15 = lane & 15, lq = lane >> 4, lk8 = lq * 8;
  const bool set1 = (int)blockIdx.x < nb1;
  // --- fused BN finalize (redundant per block; reads hot L2 partials) ---
  {
    const int col = tid & 127, half = tid >> 7;
    const int b0 = set1 ? 0 : nb1;
    const int nb = set1 ? nb1 : (nblk - nb1);
    float s = 0.f, q = 0.f;
#pragma unroll 4
    for (int b = half; b < nb; b += 2) {
      s += pS[(size_t)(b0 + b) * HID + col];
      q += pQ[(size_t)(b0 + b) * HID + col];
    }
    t0[half][col] = s;
    t1[half][col] = q;
  }
  __syncthreads();
  if (tid < HID) {
    const float s = t0[0][tid] + t0[1][tid];
    const float q = t1[0][tid] + t1[1][tid];
    const float n = set1 ? n1c : n2c;
    const float mean = s / n;
    const float var = q / n - mean * mean;
    const float rstd = rsqrtf(var + EPSV);
    const float scale = gamma[tid] * rstd;
    s_sc[tid] = scale;
    s_sh[tid] = beta[tid] - mean * scale;
  }
  __syncthreads();
  // --- GEMM2 body ---
  const int row0 = (int)blockIdx.x * 64 + wid * 16;
  const unsigned short* hptr = H + (size_t)(row0 + l15) * HID + lk8;
  f32x4 acc[8];
#pragma unroll
  for (int f = 0; f < 8; ++f) acc[f] = (f32x4){0.f, 0.f, 0.f, 0.f};
#pragma unroll
  for (int s = 0; s < 4; ++s) {
    const int k = s * 32 + lk8;
    const bf16x8 hv = *(const bf16x8*)(hptr + s * 32);
    const float4 c0 = *(const float4*)&s_sc[k];
    const float4 c1 = *(const float4*)&s_sc[k + 4];
    const float4 d0 = *(const float4*)&s_sh[k];
    const float4 d1 = *(const float4*)&s_sh[k + 4];
    const float cc[8] = {c0.x, c0.y, c0.z, c0.w, c1.x, c1.y, c1.z, c1.w};
    const float dd[8] = {d0.x, d0.y, d0.z, d0.w, d1.x, d1.y, d1.z, d1.w};
    bf16x8 bfr;
#pragma unroll
    for (int i = 0; i < 8; ++i) {
      const float a = fmaxf(fmaf(bf2f((unsigned short)hv[i]), cc[i], dd[i]), 0.f);
      bfr[i] = (short)f2bf(a);
    }
#pragma unroll
    for (int f = 0; f < 8; ++f) {
      const bf16x8 afr = *(const bf16x8*)(W2T + (size_t)(f * 16 + l15) * HID + k);
      acc[f] = __builtin_amdgcn_mfma_f32_16x16x32_bf16(afr, bfr, acc[f], 0, 0, 0);
    }
  }
  float rn = 0.f;
#pragma unroll
  for (int f = 0; f < 8; ++f) {
    rn += acc[f][0] * acc[f][0] + acc[f][1] * acc[f][1] +
          acc[f][2] * acc[f][2] + acc[f][3] * acc[f][3];
    ushort4 z4 = {f2bf(acc[f][0]), f2bf(acc[f][1]), f2bf(acc[f][2]), f2bf(acc[f][3])};
    *(ushort4*)(Z + (size_t)(row0 + l15) * HID + f * 16 + lq * 4) = z4;
  }
  rn += __shfl_xor(rn, 16, 64);
  rn += __shfl_xor(rn, 32, 64);
  if (lane < 16) nrm[row0 + l15] = rn;
}

// ---------------- dist: D = n1[i]+n2[j]-2*Z1@Z2^T, float4 stores, XCD swizzle ----------
__global__ __launch_bounds__(256) void k_dist(const unsigned short* __restrict__ Z1b,
                                              const unsigned short* __restrict__ Z2b,
                                              const float* __restrict__ n1,
                                              const float* __restrict__ n2,
                                              float* __restrict__ D, int NY, int ntx) {
  const int nwg = (int)gridDim.x;
  const int cpx = nwg >> 3;
  const int bid = (int)blockIdx.x;
  const int wgid = (bid & 7) * cpx + (bid >> 3);
  const int tby = wgid / ntx, tbx = wgid - tby * ntx;

  const int tid = threadIdx.x;
  const int wid = tid >> 6, lane = tid & 63;
  const int wr = wid >> 1, wc = wid & 1;
  const int rowB = tby * 128 + wr * 64;
  const int colB = tbx * 128 + wc * 64;
  const int l15 = lane & 15, lq = lane >> 4;
  const int lk = lq * 8;
  const unsigned short* Arow = Z1b + (size_t)(rowB + l15) * HID + lk;
  const unsigned short* Brow = Z2b + (size_t)(colB + l15) * HID + lk;
  f32x4 acc[4][4];
#pragma unroll
  for (int i = 0; i < 4; ++i)
#pragma unroll
    for (int j = 0; j < 4; ++j) acc[i][j] = (f32x4){0.f, 0.f, 0.f, 0.f};
#pragma unroll
  for (int s = 0; s < 4; ++s) {
    bf16x8 a[4], b[4];
#pragma unroll
    for (int i = 0; i < 4; ++i) a[i] = *(const bf16x8*)(Arow + (size_t)i * 16 * HID + s * 32);
#pragma unroll
    for (int j = 0; j < 4; ++j) b[j] = *(const bf16x8*)(Brow + (size_t)j * 16 * HID + s * 32);
#pragma unroll
    for (int i = 0; i < 4; ++i)
#pragma unroll
      for (int j = 0; j < 4; ++j)
        acc[i][j] = __builtin_amdgcn_mfma_f32_16x16x32_bf16(b[j], a[i], acc[i][j], 0, 0, 0);
  }
  const int cq = lq * 4;
  float na[4];
#pragma unroll
  for (int i = 0; i < 4; ++i) na[i] = n1[rowB + i * 16 + l15];
#pragma unroll
  for (int j = 0; j < 4; ++j) {
    const float4 nbv = *(const float4*)(n2 + colB + j * 16 + cq);
#pragma unroll
    for (int i = 0; i < 4; ++i) {
      float4 o;
      o.x = na[i] + nbv.x - 2.f * acc[i][j][0];
      o.y = na[i] + nbv.y - 2.f * acc[i][j][1];
      o.z = na[i] + nbv.z - 2.f * acc[i][j][2];
      o.w = na[i] + nbv.w - 2.f * acc[i][j][3];
      *(float4*)(D + (size_t)(rowB + i * 16 + l15) * NY + colB + j * 16 + cq) = o;
    }
  }
}

extern "C" void kernel_launch(void* const* d_in, const int* in_sizes, int n_in,
                              void* d_out, int out_size, void* d_ws, size_t ws_size,
                              hipStream_t stream) {
  const float* variations = (const float*)d_in[0];
  const float* exemplar   = (const float*)d_in[1];
  const float* w1         = (const float*)d_in[2];
  const float* gamma      = (const float*)d_in[3];
  const float* beta       = (const float*)d_in[4];
  const float* w2         = (const float*)d_in[5];
  float* D = (float*)d_out;

  const int nx = in_sizes[0] / LAT;  // 8192
  const int ny = in_sizes[1] / LAT;  // 2048
  const int nrows = nx + ny;         // 10240
  const int nbb = nrows / 64;        // 160
  const int nb1 = nx / 64;           // 128

  char* p = (char*)d_ws;
  unsigned short* Xb  = (unsigned short*)p; p += (size_t)nrows * LAT * 2;  // 10.5 MB
  unsigned short* Hb  = (unsigned short*)p; p += (size_t)nrows * HID * 2;
  unsigned short* Zb  = (unsigned short*)p; p += (size_t)nrows * HID * 2;
  unsigned short* W1T = (unsigned short*)p; p += (size_t)LAT * HID * 2;
  unsigned short* W2T = (unsigned short*)p; p += (size_t)HID * HID * 2;
  float* pS = (float*)p;  p += (size_t)nbb * HID * 4;
  float* pQ = (float*)p;  p += (size_t)nbb * HID * 4;
  float* nrmAll = (float*)p; p += (size_t)nrows * 4;
  float* n1v = nrmAll;
  float* n2v = nrmAll + nx;
  unsigned short* Z1b = Zb;
  unsigned short* Z2b = Zb + (size_t)nx * HID;

  const int xblocks = (nrows * LAT) / 2048;  // 2560
  k_prep<<<20 + xblocks, 256, 0, stream>>>(w1, w2, variations, exemplar, nx,
                                           W1T, W2T, Xb);
  k_gemm1<<<nbb, 256, 0, stream>>>(Xb, W1T, Hb, pS, pQ);
  k_gemm2<<<nbb, 256, 0, stream>>>(Hb, W2T, pS, pQ, gamma, beta, Zb, nrmAll,
                                   nb1, nbb, (float)nx, (float)ny);
  const int ntx = ny / 128;                  // 16
  const int nwg = (nx / 128) * ntx;          // 1024
  k_dist<<<nwg, 256, 0, stream>>>(Z1b, Z2b, n1v, n2v, D, ny, ntx);
}

// Round 12
// 62.585 us; speedup vs baseline: 1.5491x; 1.0821x over previous
//
#include <hip/hip_runtime.h>
#include <hip/hip_bf16.h>

// proto_net_loss, 4 dispatches:
//  prep:   W1P (fragment-packed bf16 W1), W2T (transposed bf16 W2),
//          XbP (fragment-packed bf16 X) — all loads in gemm1 become 1KB-contiguous
//  gemm1:  H(bf16) = X @ W1 via MFMA, fragment-linear operand streams,
//          fused per-block BN partial stats (160 blocks x 4 waves)
//  gemm2:  [BN finalize fused in head] Z(bf16) = relu(H*sc+sh) @ W2 + f32 row norms
//  dist:   D = n1[i]+n2[j]-2*Z1@Z2^T; swapped-operand MFMA, float4 stores, XCD swizzle

#define LAT 512
#define HID 128
#define EPSV 1e-5f

typedef __attribute__((ext_vector_type(8))) short bf16x8;
typedef __attribute__((ext_vector_type(4))) float f32x4;

__device__ __forceinline__ unsigned short f2bf(float x) {  // RTNE
  unsigned int u = __builtin_bit_cast(unsigned int, x);
  return (unsigned short)((u + 0x7fffu + ((u >> 16) & 1u)) >> 16);
}
__device__ __forceinline__ float bf2f(unsigned short h) {
  unsigned int u = ((unsigned int)h) << 16;
  return __builtin_bit_cast(float, u);
}

// ---------------- prep ----------------
// blocks 0..15:  W1 -> W1P fragment-packed:  W1P[(((f*16+t)*16+l15)*4+lq)*8 + j]
//                = W1T[n=f*16+l15][k=t*32+lq*8+j]
// blocks 16..19: W2 -> W2T row-major transposed (gemm2 layout unchanged)
// blocks >=20:   X -> XbP fragment-packed:    XbP[(((st*16+t)*16+l15)*4+lq)*8 + j]
//                = X[row=st*16+l15][k=t*32+lq*8+j]
__global__ __launch_bounds__(256) void k_prep(const float* __restrict__ W1,
                                              const float* __restrict__ W2,
                                              const float* __restrict__ X1,
                                              const float* __restrict__ X2, int nx,
                                              unsigned short* __restrict__ W1P,
                                              unsigned short* __restrict__ W2T,
                                              unsigned short* __restrict__ XbP) {
  __shared__ float T[64][65];
  const int t = threadIdx.x;
  int bi = blockIdx.x;
  if (bi >= 20) {
    // X conversion into fragment-packed layout (8 elems/thread, aligned to lq group)
    const size_t base = (size_t)(bi - 20) * 2048 + (size_t)t * 8;
    const size_t nxe = (size_t)nx * LAT;
    const float* src = (base < nxe) ? (X1 + base) : (X2 + (base - nxe));
    const float4 a = *(const float4*)src;
    const float4 b = *(const float4*)(src + 4);
    const int row = (int)(base >> 9);   // /512
    const int k = (int)(base & 511);
    const int st = row >> 4, l15 = row & 15;
    const int tf = k >> 5, lq = (k >> 3) & 3;
    const size_t off = ((((size_t)st * 16 + tf) * 16 + l15) * 4 + lq) * 8;
    const ushort4 o0 = {f2bf(a.x), f2bf(a.y), f2bf(a.z), f2bf(a.w)};
    const ushort4 o1 = {f2bf(b.x), f2bf(b.y), f2bf(b.z), f2bf(b.w)};
    *(ushort4*)(XbP + off) = o0;
    *(ushort4*)(XbP + off + 4) = o1;
    return;
  }
  if (bi < 16) {  // W1 tile -> W1P
    const int tk = bi >> 1, tn = bi & 1;
    const int k0 = tk * 64, n0 = tn * 64;
    {
      const int rr = t >> 4, cc = (t & 15) * 4;
#pragma unroll
      for (int i = 0; i < 4; ++i) {
        const int r = rr + i * 16;
        const float4 v = *(const float4*)(W1 + (size_t)(k0 + r) * HID + n0 + cc);
        T[cc + 0][r] = v.x; T[cc + 1][r] = v.y; T[cc + 2][r] = v.z; T[cc + 3][r] = v.w;
      }
    }
    __syncthreads();
    {
      const int nn = t >> 2, q = (t & 3) * 16;  // n = n0+nn, k = k0+q+0..15
      const int n = n0 + nn;
      const int f = n >> 4, l15 = n & 15;
#pragma unroll
      for (int e8 = 0; e8 < 2; ++e8) {
        const int kq = q + e8 * 8;       // k within tile
        const int kk = k0 + kq;          // global k
        const int tf = kk >> 5, lq = (kk >> 3) & 3;
        const size_t off = ((((size_t)f * 16 + tf) * 16 + l15) * 4 + lq) * 8;
        const ushort4 lo = {f2bf(T[nn][kq + 0]), f2bf(T[nn][kq + 1]),
                            f2bf(T[nn][kq + 2]), f2bf(T[nn][kq + 3])};
        const ushort4 hi = {f2bf(T[nn][kq + 4]), f2bf(T[nn][kq + 5]),
                            f2bf(T[nn][kq + 6]), f2bf(T[nn][kq + 7])};
        *(ushort4*)(W1P + off) = lo;
        *(ushort4*)(W1P + off + 4) = hi;
      }
    }
  } else {  // W2 tile -> W2T row-major transposed (unchanged layout)
    bi -= 16;
    const int tk = bi >> 1, tn = bi & 1;
    const int k0 = tk * 64, n0 = tn * 64;
    {
      const int rr = t >> 4, cc = (t & 15) * 4;
#pragma unroll
      for (int i = 0; i < 4; ++i) {
        const int r = rr + i * 16;
        const float4 v = *(const float4*)(W2 + (size_t)(k0 + r) * HID + n0 + cc);
        T[cc + 0][r] = v.x; T[cc + 1][r] = v.y; T[cc + 2][r] = v.z; T[cc + 3][r] = v.w;
      }
    }
    __syncthreads();
    {
      const int nn = t >> 2, q = (t & 3) * 16;
      unsigned short* dp = W2T + (size_t)(n0 + nn) * HID + k0 + q;
#pragma unroll
      for (int j = 0; j < 4; ++j) {
        ushort4 o = {f2bf(T[nn][q + j * 4 + 0]), f2bf(T[nn][q + j * 4 + 1]),
                     f2bf(T[nn][q + j * 4 + 2]), f2bf(T[nn][q + j * 4 + 3])};
        *(ushort4*)(dp + j * 4) = o;
      }
    }
  }
}

// ---------------- gemm1: H = X @ W1, fragment-linear streams + partial stats --------
// 4 waves/block, wave = 16 rows x 128 cols, K=512. grid = 160. All loads 1KB-coalesced.
__global__ __launch_bounds__(256) void k_gemm1(
    const unsigned short* __restrict__ XbP,
    const unsigned short* __restrict__ W1P, unsigned short* __restrict__ H,
    float* __restrict__ pS, float* __restrict__ pQ) {
  __shared__ float sS[16][HID], sQ[16][HID];
  const int tid = threadIdx.x, wid = tid >> 6, lane = tid & 63;
  const int l15 = lane & 15, lq = lane >> 4;
  const int row0 = (int)blockIdx.x * 64 + wid * 16;
  const int st = row0 >> 4;
  const unsigned short* xp = XbP + (((size_t)st * 16 * 16 + l15) * 4 + lq) * 8;
  const unsigned short* wp = W1P + (((size_t)l15) * 4 + lq) * 8;
  f32x4 acc[8];
#pragma unroll
  for (int f = 0; f < 8; ++f) acc[f] = (f32x4){0.f, 0.f, 0.f, 0.f};

#pragma unroll
  for (int t = 0; t < 16; ++t) {
    const bf16x8 xv = *(const bf16x8*)(xp + (size_t)t * 512);
#pragma unroll
    for (int f = 0; f < 8; ++f) {
      const bf16x8 afr = *(const bf16x8*)(wp + (size_t)(f * 16 + t) * 512);
      acc[f] = __builtin_amdgcn_mfma_f32_16x16x32_bf16(afr, xv, acc[f], 0, 0, 0);
    }
  }
  // store H row-major bf16: lane holds H[m=row0+l15][n=f*16+lq*4+r]
#pragma unroll
  for (int f = 0; f < 8; ++f) {
    ushort4 hz = {f2bf(acc[f][0]), f2bf(acc[f][1]), f2bf(acc[f][2]), f2bf(acc[f][3])};
    *(ushort4*)(H + (size_t)(row0 + l15) * HID + f * 16 + lq * 4) = hz;
  }
  // partial stats: 2 shfl stages then LDS fold
#pragma unroll
  for (int f = 0; f < 8; ++f) {
    f32x4 s = acc[f];
    f32x4 q = acc[f] * acc[f];
#pragma unroll
    for (int r = 0; r < 4; ++r) {
      s[r] += __shfl_xor(s[r], 1, 64);
      q[r] += __shfl_xor(q[r], 1, 64);
      s[r] += __shfl_xor(s[r], 2, 64);
      q[r] += __shfl_xor(q[r], 2, 64);
    }
    if ((l15 & 3) == 0) {
      *(f32x4*)&sS[wid * 4 + (l15 >> 2)][f * 16 + lq * 4] = s;
      *(f32x4*)&sQ[wid * 4 + (l15 >> 2)][f * 16 + lq * 4] = q;
    }
  }
  __syncthreads();
  if (tid < HID) {
    float s = 0.f, q = 0.f;
#pragma unroll
    for (int r = 0; r < 16; ++r) { s += sS[r][tid]; q += sQ[r][tid]; }
    pS[(size_t)blockIdx.x * HID + tid] = s;
    pQ[(size_t)blockIdx.x * HID + tid] = q;
  }
}

// ---------------- gemm2: finalize-in-head + Z(bf16) = relu(H*sc+sh)@W2 + row norms ----
__global__ __launch_bounds__(256) void k_gemm2(
    const unsigned short* __restrict__ H,
    const unsigned short* __restrict__ W2T,
    const float* __restrict__ pS, const float* __restrict__ pQ,
    const float* __restrict__ gamma, const float* __restrict__ beta,
    unsigned short* __restrict__ Z, float* __restrict__ nrm,
    int nb1, int nblk, float n1c, float n2c) {
  __shared__ float s_sc[HID], s_sh[HID];
  __shared__ float t0[2][HID], t1[2][HID];
  const int tid = threadIdx.x, wid = tid >> 6, lane = tid & 63;
  const int l15 = lane & 15, lq = lane >> 4, lk8 = lq * 8;
  const bool set1 = (int)blockIdx.x < nb1;
  {
    const int col = tid & 127, half = tid >> 7;
    const int b0 = set1 ? 0 : nb1;
    const int nb = set1 ? nb1 : (nblk - nb1);
    float s = 0.f, q = 0.f;
#pragma unroll 4
    for (int b = half; b < nb; b += 2) {
      s += pS[(size_t)(b0 + b) * HID + col];
      q += pQ[(size_t)(b0 + b) * HID + col];
    }
    t0[half][col] = s;
    t1[half][col] = q;
  }
  __syncthreads();
  if (tid < HID) {
    const float s = t0[0][tid] + t0[1][tid];
    const float q = t1[0][tid] + t1[1][tid];
    const float n = set1 ? n1c : n2c;
    const float mean = s / n;
    const float var = q / n - mean * mean;
    const float rstd = rsqrtf(var + EPSV);
    const float scale = gamma[tid] * rstd;
    s_sc[tid] = scale;
    s_sh[tid] = beta[tid] - mean * scale;
  }
  __syncthreads();
  const int row0 = (int)blockIdx.x * 64 + wid * 16;
  const unsigned short* hptr = H + (size_t)(row0 + l15) * HID + lk8;
  f32x4 acc[8];
#pragma unroll
  for (int f = 0; f < 8; ++f) acc[f] = (f32x4){0.f, 0.f, 0.f, 0.f};
#pragma unroll
  for (int s = 0; s < 4; ++s) {
    const int k = s * 32 + lk8;
    const bf16x8 hv = *(const bf16x8*)(hptr + s * 32);
    const float4 c0 = *(const float4*)&s_sc[k];
    const float4 c1 = *(const float4*)&s_sc[k + 4];
    const float4 d0 = *(const float4*)&s_sh[k];
    const float4 d1 = *(const float4*)&s_sh[k + 4];
    const float cc[8] = {c0.x, c0.y, c0.z, c0.w, c1.x, c1.y, c1.z, c1.w};
    const float dd[8] = {d0.x, d0.y, d0.z, d0.w, d1.x, d1.y, d1.z, d1.w};
    bf16x8 bfr;
#pragma unroll
    for (int i = 0; i < 8; ++i) {
      const float a = fmaxf(fmaf(bf2f((unsigned short)hv[i]), cc[i], dd[i]), 0.f);
      bfr[i] = (short)f2bf(a);
    }
#pragma unroll
    for (int f = 0; f < 8; ++f) {
      const bf16x8 afr = *(const bf16x8*)(W2T + (size_t)(f * 16 + l15) * HID + k);
      acc[f] = __builtin_amdgcn_mfma_f32_16x16x32_bf16(afr, bfr, acc[f], 0, 0, 0);
    }
  }
  float rn = 0.f;
#pragma unroll
  for (int f = 0; f < 8; ++f) {
    rn += acc[f][0] * acc[f][0] + acc[f][1] * acc[f][1] +
          acc[f][2] * acc[f][2] + acc[f][3] * acc[f][3];
    ushort4 z4 = {f2bf(acc[f][0]), f2bf(acc[f][1]), f2bf(acc[f][2]), f2bf(acc[f][3])};
    *(ushort4*)(Z + (size_t)(row0 + l15) * HID + f * 16 + lq * 4) = z4;
  }
  rn += __shfl_xor(rn, 16, 64);
  rn += __shfl_xor(rn, 32, 64);
  if (lane < 16) nrm[row0 + l15] = rn;
}

// ---------------- dist: D = n1[i]+n2[j]-2*Z1@Z2^T, float4 stores, XCD swizzle ----------
__global__ __launch_bounds__(256) void k_dist(const unsigned short* __restrict__ Z1b,
                                              const unsigned short* __restrict__ Z2b,
                                              const float* __restrict__ n1,
                                              const float* __restrict__ n2,
                                              float* __restrict__ D, int NY, int ntx) {
  const int nwg = (int)gridDim.x;
  const int cpx = nwg >> 3;
  const int bid = (int)blockIdx.x;
  const int wgid = (bid & 7) * cpx + (bid >> 3);
  const int tby = wgid / ntx, tbx = wgid - tby * ntx;

  const int tid = threadIdx.x;
  const int wid = tid >> 6, lane = tid & 63;
  const int wr = wid >> 1, wc = wid & 1;
  const int rowB = tby * 128 + wr * 64;
  const int colB = tbx * 128 + wc * 64;
  const int l15 = lane & 15, lq = lane >> 4;
  const int lk = lq * 8;
  const unsigned short* Arow = Z1b + (size_t)(rowB + l15) * HID + lk;
  const unsigned short* Brow = Z2b + (size_t)(colB + l15) * HID + lk;
  f32x4 acc[4][4];
#pragma unroll
  for (int i = 0; i < 4; ++i)
#pragma unroll
    for (int j = 0; j < 4; ++j) acc[i][j] = (f32x4){0.f, 0.f, 0.f, 0.f};
#pragma unroll
  for (int s = 0; s < 4; ++s) {
    bf16x8 a[4], b[4];
#pragma unroll
    for (int i = 0; i < 4; ++i) a[i] = *(const bf16x8*)(Arow + (size_t)i * 16 * HID + s * 32);
#pragma unroll
    for (int j = 0; j < 4; ++j) b[j] = *(const bf16x8*)(Brow + (size_t)j * 16 * HID + s * 32);
#pragma unroll
    for (int i = 0; i < 4; ++i)
#pragma unroll
      for (int j = 0; j < 4; ++j)
        acc[i][j] = __builtin_amdgcn_mfma_f32_16x16x32_bf16(b[j], a[i], acc[i][j], 0, 0, 0);
  }
  const int cq = lq * 4;
  float na[4];
#pragma unroll
  for (int i = 0; i < 4; ++i) na[i] = n1[rowB + i * 16 + l15];
#pragma unroll
  for (int j = 0; j < 4; ++j) {
    const float4 nbv = *(const float4*)(n2 + colB + j * 16 + cq);
#pragma unroll
    for (int i = 0; i < 4; ++i) {
      float4 o;
      o.x = na[i] + nbv.x - 2.f * acc[i][j][0];
      o.y = na[i] + nbv.y - 2.f * acc[i][j][1];
      o.z = na[i] + nbv.z - 2.f * acc[i][j][2];
      o.w = na[i] + nbv.w - 2.f * acc[i][j][3];
      *(float4*)(D + (size_t)(rowB + i * 16 + l15) * NY + colB + j * 16 + cq) = o;
    }
  }
}

extern "C" void kernel_launch(void* const* d_in, const int* in_sizes, int n_in,
                              void* d_out, int out_size, void* d_ws, size_t ws_size,
                              hipStream_t stream) {
  const float* variations = (const float*)d_in[0];
  const float* exemplar   = (const float*)d_in[1];
  const float* w1         = (const float*)d_in[2];
  const float* gamma      = (const float*)d_in[3];
  const float* beta       = (const float*)d_in[4];
  const float* w2         = (const float*)d_in[5];
  float* D = (float*)d_out;

  const int nx = in_sizes[0] / LAT;  // 8192
  const int ny = in_sizes[1] / LAT;  // 2048
  const int nrows = nx + ny;         // 10240
  const int nbb = nrows / 64;        // 160
  const int nb1 = nx / 64;           // 128

  char* p = (char*)d_ws;
  unsigned short* XbP = (unsigned short*)p; p += (size_t)nrows * LAT * 2;  // 10.5 MB
  unsigned short* Hb  = (unsigned short*)p; p += (size_t)nrows * HID * 2;
  unsigned short* Zb  = (unsigned short*)p; p += (size_t)nrows * HID * 2;
  unsigned short* W1P = (unsigned short*)p; p += (size_t)LAT * HID * 2;
  unsigned short* W2T = (unsigned short*)p; p += (size_t)HID * HID * 2;
  float* pS = (float*)p;  p += (size_t)nbb * HID * 4;
  float* pQ = (float*)p;  p += (size_t)nbb * HID * 4;
  float* nrmAll = (float*)p; p += (size_t)nrows * 4;
  float* n1v = nrmAll;
  float* n2v = nrmAll + nx;
  unsigned short* Z1b = Zb;
  unsigned short* Z2b = Zb + (size_t)nx * HID;

  const int xblocks = (nrows * LAT) / 2048;  // 2560
  k_prep<<<20 + xblocks, 256, 0, stream>>>(w1, w2, variations, exemplar, nx,
                                           W1P, W2T, XbP);
  k_gemm1<<<nbb, 256, 0, stream>>>(XbP, W1P, Hb, pS, pQ);
  k_gemm2<<<nbb, 256, 0, stream>>>(Hb, W2T, pS, pQ, gamma, beta, Zb, nrmAll,
                                   nb1, nbb, (float)nx, (float)ny);
  const int ntx = ny / 128;                  // 16
  const int nwg = (nx / 128) * ntx;          // 1024
  k_dist<<<nwg, 256, 0, stream>>>(Z1b, Z2b, n1v, n2v, D, ny, ntx);
}

// Round 13
// 58.811 us; speedup vs baseline: 1.6484x; 1.0642x over previous
//
#include <hip/hip_runtime.h>
#include <hip/hip_bf16.h>

// proto_net_loss, 4 dispatches. ALL MFMA operand tensors fragment-packed:
//  packed layout for [rows][128] bf16: off(row,k) = (row>>4)*2048 + (k>>5)*512
//                                      + (row&15)*32 + ((k>>3)&3)*8 + (k&7)
//  -> every MFMA fragment load (gemm1 X/W1, gemm2 H, dist Z1/Z2) is 1KB-contiguous.
//  prep:   W1P, W2T, XbP (fragment-packed bf16)
//  gemm1:  H(packed bf16) = X @ W1 + per-block BN partial stats
//  gemm2:  [BN finalize in head] Z(packed bf16) = relu(H*sc+sh) @ W2 + f32 row norms
//  dist:   D = n1[i]+n2[j]-2*Z1@Z2^T; packed Z loads, float4 stores, XCD swizzle

#define LAT 512
#define HID 128
#define EPSV 1e-5f

typedef __attribute__((ext_vector_type(8))) short bf16x8;
typedef __attribute__((ext_vector_type(4))) float f32x4;

__device__ __forceinline__ unsigned short f2bf(float x) {  // RTNE
  unsigned int u = __builtin_bit_cast(unsigned int, x);
  return (unsigned short)((u + 0x7fffu + ((u >> 16) & 1u)) >> 16);
}
__device__ __forceinline__ float bf2f(unsigned short h) {
  unsigned int u = ((unsigned int)h) << 16;
  return __builtin_bit_cast(float, u);
}
// element offset for the ushort4 store of acc[f][0..3] by lane (l15,lq) into a
// fragment-packed [rows][128] tensor (verified: holds T[strip*16+l15][f*16+lq*4+r])
__device__ __forceinline__ size_t pack4_off(int strip, int f, int l15, int lq) {
  return (size_t)strip * 2048 + (size_t)(f >> 1) * 512 + (size_t)l15 * 32 +
         (size_t)(((f & 1) * 2 + (lq >> 1)) * 8 + (lq & 1) * 4);
}

// ---------------- prep: W1P fragment-packed, W2T transposed, XbP fragment-packed ----
__global__ __launch_bounds__(256) void k_prep(const float* __restrict__ W1,
                                              const float* __restrict__ W2,
                                              const float* __restrict__ X1,
                                              const float* __restrict__ X2, int nx,
                                              unsigned short* __restrict__ W1P,
                                              unsigned short* __restrict__ W2T,
                                              unsigned short* __restrict__ XbP) {
  __shared__ float T[64][65];
  const int t = threadIdx.x;
  int bi = blockIdx.x;
  if (bi >= 20) {
    const size_t base = (size_t)(bi - 20) * 2048 + (size_t)t * 8;
    const size_t nxe = (size_t)nx * LAT;
    const float* src = (base < nxe) ? (X1 + base) : (X2 + (base - nxe));
    const float4 a = *(const float4*)src;
    const float4 b = *(const float4*)(src + 4);
    const int row = (int)(base >> 9);
    const int k = (int)(base & 511);
    const int st = row >> 4, l15 = row & 15;
    const int tf = k >> 5, lq = (k >> 3) & 3;
    const size_t off = ((((size_t)st * 16 + tf) * 16 + l15) * 4 + lq) * 8;
    const ushort4 o0 = {f2bf(a.x), f2bf(a.y), f2bf(a.z), f2bf(a.w)};
    const ushort4 o1 = {f2bf(b.x), f2bf(b.y), f2bf(b.z), f2bf(b.w)};
    *(ushort4*)(XbP + off) = o0;
    *(ushort4*)(XbP + off + 4) = o1;
    return;
  }
  if (bi < 16) {  // W1 tile -> W1P
    const int tk = bi >> 1, tn = bi & 1;
    const int k0 = tk * 64, n0 = tn * 64;
    {
      const int rr = t >> 4, cc = (t & 15) * 4;
#pragma unroll
      for (int i = 0; i < 4; ++i) {
        const int r = rr + i * 16;
        const float4 v = *(const float4*)(W1 + (size_t)(k0 + r) * HID + n0 + cc);
        T[cc + 0][r] = v.x; T[cc + 1][r] = v.y; T[cc + 2][r] = v.z; T[cc + 3][r] = v.w;
      }
    }
    __syncthreads();
    {
      const int nn = t >> 2, q = (t & 3) * 16;
      const int n = n0 + nn;
      const int f = n >> 4, l15 = n & 15;
#pragma unroll
      for (int e8 = 0; e8 < 2; ++e8) {
        const int kq = q + e8 * 8;
        const int kk = k0 + kq;
        const int tf = kk >> 5, lq = (kk >> 3) & 3;
        const size_t off = ((((size_t)f * 16 + tf) * 16 + l15) * 4 + lq) * 8;
        const ushort4 lo = {f2bf(T[nn][kq + 0]), f2bf(T[nn][kq + 1]),
                            f2bf(T[nn][kq + 2]), f2bf(T[nn][kq + 3])};
        const ushort4 hi = {f2bf(T[nn][kq + 4]), f2bf(T[nn][kq + 5]),
                            f2bf(T[nn][kq + 6]), f2bf(T[nn][kq + 7])};
        *(ushort4*)(W1P + off) = lo;
        *(ushort4*)(W1P + off + 4) = hi;
      }
    }
  } else {  // W2 -> W2T row-major transposed
    bi -= 16;
    const int tk = bi >> 1, tn = bi & 1;
    const int k0 = tk * 64, n0 = tn * 64;
    {
      const int rr = t >> 4, cc = (t & 15) * 4;
#pragma unroll
      for (int i = 0; i < 4; ++i) {
        const int r = rr + i * 16;
        const float4 v = *(const float4*)(W2 + (size_t)(k0 + r) * HID + n0 + cc);
        T[cc + 0][r] = v.x; T[cc + 1][r] = v.y; T[cc + 2][r] = v.z; T[cc + 3][r] = v.w;
      }
    }
    __syncthreads();
    {
      const int nn = t >> 2, q = (t & 3) * 16;
      unsigned short* dp = W2T + (size_t)(n0 + nn) * HID + k0 + q;
#pragma unroll
      for (int j = 0; j < 4; ++j) {
        ushort4 o = {f2bf(T[nn][q + j * 4 + 0]), f2bf(T[nn][q + j * 4 + 1]),
                     f2bf(T[nn][q + j * 4 + 2]), f2bf(T[nn][q + j * 4 + 3])};
        *(ushort4*)(dp + j * 4) = o;
      }
    }
  }
}

// ---------------- gemm1: H(packed) = X @ W1 + partial stats ----------------
__global__ __launch_bounds__(256) void k_gemm1(
    const unsigned short* __restrict__ XbP,
    const unsigned short* __restrict__ W1P, unsigned short* __restrict__ H,
    float* __restrict__ pS, float* __restrict__ pQ) {
  __shared__ float sS[16][HID], sQ[16][HID];
  const int tid = threadIdx.x, wid = tid >> 6, lane = tid & 63;
  const int l15 = lane & 15, lq = lane >> 4;
  const int row0 = (int)blockIdx.x * 64 + wid * 16;
  const int strip = row0 >> 4;
  const unsigned short* xp = XbP + (((size_t)strip * 16 * 16 + l15) * 4 + lq) * 8;
  const unsigned short* wp = W1P + (((size_t)l15) * 4 + lq) * 8;
  f32x4 acc[8];
#pragma unroll
  for (int f = 0; f < 8; ++f) acc[f] = (f32x4){0.f, 0.f, 0.f, 0.f};

#pragma unroll
  for (int t = 0; t < 16; ++t) {
    const bf16x8 xv = *(const bf16x8*)(xp + (size_t)t * 512);
#pragma unroll
    for (int f = 0; f < 8; ++f) {
      const bf16x8 afr = *(const bf16x8*)(wp + (size_t)(f * 16 + t) * 512);
      acc[f] = __builtin_amdgcn_mfma_f32_16x16x32_bf16(afr, xv, acc[f], 0, 0, 0);
    }
  }
  // store H fragment-packed
#pragma unroll
  for (int f = 0; f < 8; ++f) {
    ushort4 hz = {f2bf(acc[f][0]), f2bf(acc[f][1]), f2bf(acc[f][2]), f2bf(acc[f][3])};
    *(ushort4*)(H + pack4_off(strip, f, l15, lq)) = hz;
  }
  // partial stats
#pragma unroll
  for (int f = 0; f < 8; ++f) {
    f32x4 s = acc[f];
    f32x4 q = acc[f] * acc[f];
#pragma unroll
    for (int r = 0; r < 4; ++r) {
      s[r] += __shfl_xor(s[r], 1, 64);
      q[r] += __shfl_xor(q[r], 1, 64);
      s[r] += __shfl_xor(s[r], 2, 64);
      q[r] += __shfl_xor(q[r], 2, 64);
    }
    if ((l15 & 3) == 0) {
      *(f32x4*)&sS[wid * 4 + (l15 >> 2)][f * 16 + lq * 4] = s;
      *(f32x4*)&sQ[wid * 4 + (l15 >> 2)][f * 16 + lq * 4] = q;
    }
  }
  __syncthreads();
  if (tid < HID) {
    float s = 0.f, q = 0.f;
#pragma unroll
    for (int r = 0; r < 16; ++r) { s += sS[r][tid]; q += sQ[r][tid]; }
    pS[(size_t)blockIdx.x * HID + tid] = s;
    pQ[(size_t)blockIdx.x * HID + tid] = q;
  }
}

// ---------------- gemm2: finalize-in-head + Z(packed) = relu(H*sc+sh)@W2 + norms ----
__global__ __launch_bounds__(256) void k_gemm2(
    const unsigned short* __restrict__ H,
    const unsigned short* __restrict__ W2T,
    const float* __restrict__ pS, const float* __restrict__ pQ,
    const float* __restrict__ gamma, const float* __restrict__ beta,
    unsigned short* __restrict__ Z, float* __restrict__ nrm,
    int nb1, int nblk, float n1c, float n2c) {
  __shared__ float s_sc[HID], s_sh[HID];
  __shared__ float t0[2][HID], t1[2][HID];
  const int tid = threadIdx.x, wid = tid >> 6, lane = tid & 63;
  const int l15 = lane & 15, lq = lane >> 4, lk8 = lq * 8;
  const bool set1 = (int)blockIdx.x < nb1;
  {
    const int col = tid & 127, half = tid >> 7;
    const int b0 = set1 ? 0 : nb1;
    const int nb = set1 ? nb1 : (nblk - nb1);
    float s = 0.f, q = 0.f;
#pragma unroll 4
    for (int b = half; b < nb; b += 2) {
      s += pS[(size_t)(b0 + b) * HID + col];
      q += pQ[(size_t)(b0 + b) * HID + col];
    }
    t0[half][col] = s;
    t1[half][col] = q;
  }
  __syncthreads();
  if (tid < HID) {
    const float s = t0[0][tid] + t0[1][tid];
    const float q = t1[0][tid] + t1[1][tid];
    const float n = set1 ? n1c : n2c;
    const float mean = s / n;
    const float var = q / n - mean * mean;
    const float rstd = rsqrtf(var + EPSV);
    const float scale = gamma[tid] * rstd;
    s_sc[tid] = scale;
    s_sh[tid] = beta[tid] - mean * scale;
  }
  __syncthreads();
  const int row0 = (int)blockIdx.x * 64 + wid * 16;
  const int strip = row0 >> 4;
  const unsigned short* hptr = H + (size_t)strip * 2048 + (size_t)l15 * 32 + lk8;
  f32x4 acc[8];
#pragma unroll
  for (int f = 0; f < 8; ++f) acc[f] = (f32x4){0.f, 0.f, 0.f, 0.f};
#pragma unroll
  for (int s = 0; s < 4; ++s) {
    const int k = s * 32 + lk8;
    const bf16x8 hv = *(const bf16x8*)(hptr + (size_t)s * 512);
    const float4 c0 = *(const float4*)&s_sc[k];
    const float4 c1 = *(const float4*)&s_sc[k + 4];
    const float4 d0 = *(const float4*)&s_sh[k];
    const float4 d1 = *(const float4*)&s_sh[k + 4];
    const float cc[8] = {c0.x, c0.y, c0.z, c0.w, c1.x, c1.y, c1.z, c1.w};
    const float dd[8] = {d0.x, d0.y, d0.z, d0.w, d1.x, d1.y, d1.z, d1.w};
    bf16x8 bfr;
#pragma unroll
    for (int i = 0; i < 8; ++i) {
      const float a = fmaxf(fmaf(bf2f((unsigned short)hv[i]), cc[i], dd[i]), 0.f);
      bfr[i] = (short)f2bf(a);
    }
#pragma unroll
    for (int f = 0; f < 8; ++f) {
      const bf16x8 afr = *(const bf16x8*)(W2T + (size_t)(f * 16 + l15) * HID + k);
      acc[f] = __builtin_amdgcn_mfma_f32_16x16x32_bf16(afr, bfr, acc[f], 0, 0, 0);
    }
  }
  float rn = 0.f;
#pragma unroll
  for (int f = 0; f < 8; ++f) {
    rn += acc[f][0] * acc[f][0] + acc[f][1] * acc[f][1] +
          acc[f][2] * acc[f][2] + acc[f][3] * acc[f][3];
    ushort4 z4 = {f2bf(acc[f][0]), f2bf(acc[f][1]), f2bf(acc[f][2]), f2bf(acc[f][3])};
    *(ushort4*)(Z + pack4_off(strip, f, l15, lq)) = z4;
  }
  rn += __shfl_xor(rn, 16, 64);
  rn += __shfl_xor(rn, 32, 64);
  if (lane < 16) nrm[row0 + l15] = rn;
}

// ---------------- dist: packed Z loads, float4 stores, XCD swizzle ----------------
__global__ __launch_bounds__(256) void k_dist(const unsigned short* __restrict__ Z1b,
                                              const unsigned short* __restrict__ Z2b,
                                              const float* __restrict__ n1,
                                              const float* __restrict__ n2,
                                              float* __restrict__ D, int NY, int ntx) {
  const int nwg = (int)gridDim.x;
  const int cpx = nwg >> 3;
  const int bid = (int)blockIdx.x;
  const int wgid = (bid & 7) * cpx + (bid >> 3);
  const int tby = wgid / ntx, tbx = wgid - tby * ntx;

  const int tid = threadIdx.x;
  const int wid = tid >> 6, lane = tid & 63;
  const int wr = wid >> 1, wc = wid & 1;
  const int rowB = tby * 128 + wr * 64;
  const int colB = tbx * 128 + wc * 64;
  const int l15 = lane & 15, lq = lane >> 4;
  const unsigned short* Ap = Z1b + (size_t)(rowB >> 4) * 2048 + (size_t)l15 * 32 + lq * 8;
  const unsigned short* Bp = Z2b + (size_t)(colB >> 4) * 2048 + (size_t)l15 * 32 + lq * 8;
  f32x4 acc[4][4];
#pragma unroll
  for (int i = 0; i < 4; ++i)
#pragma unroll
    for (int j = 0; j < 4; ++j) acc[i][j] = (f32x4){0.f, 0.f, 0.f, 0.f};
#pragma unroll
  for (int s = 0; s < 4; ++s) {
    bf16x8 a[4], b[4];
#pragma unroll
    for (int i = 0; i < 4; ++i) a[i] = *(const bf16x8*)(Ap + (size_t)i * 2048 + (size_t)s * 512);
#pragma unroll
    for (int j = 0; j < 4; ++j) b[j] = *(const bf16x8*)(Bp + (size_t)j * 2048 + (size_t)s * 512);
#pragma unroll
    for (int i = 0; i < 4; ++i)
#pragma unroll
      for (int j = 0; j < 4; ++j)
        acc[i][j] = __builtin_amdgcn_mfma_f32_16x16x32_bf16(b[j], a[i], acc[i][j], 0, 0, 0);
  }
  const int cq = lq * 4;
  float na[4];
#pragma unroll
  for (int i = 0; i < 4; ++i) na[i] = n1[rowB + i * 16 + l15];
#pragma unroll
  for (int j = 0; j < 4; ++j) {
    const float4 nbv = *(const float4*)(n2 + colB + j * 16 + cq);
#pragma unroll
    for (int i = 0; i < 4; ++i) {
      float4 o;
      o.x = na[i] + nbv.x - 2.f * acc[i][j][0];
      o.y = na[i] + nbv.y - 2.f * acc[i][j][1];
      o.z = na[i] + nbv.z - 2.f * acc[i][j][2];
      o.w = na[i] + nbv.w - 2.f * acc[i][j][3];
      *(float4*)(D + (size_t)(rowB + i * 16 + l15) * NY + colB + j * 16 + cq) = o;
    }
  }
}

extern "C" void kernel_launch(void* const* d_in, const int* in_sizes, int n_in,
                              void* d_out, int out_size, void* d_ws, size_t ws_size,
                              hipStream_t stream) {
  const float* variations = (const float*)d_in[0];
  const float* exemplar   = (const float*)d_in[1];
  const float* w1         = (const float*)d_in[2];
  const float* gamma      = (const float*)d_in[3];
  const float* beta       = (const float*)d_in[4];
  const float* w2         = (const float*)d_in[5];
  float* D = (float*)d_out;

  const int nx = in_sizes[0] / LAT;  // 8192
  const int ny = in_sizes[1] / LAT;  // 2048
  const int nrows = nx + ny;         // 10240
  const int nbb = nrows / 64;        // 160
  const int nb1 = nx / 64;           // 128

  char* p = (char*)d_ws;
  unsigned short* XbP = (unsigned short*)p; p += (size_t)nrows * LAT * 2;
  unsigned short* Hb  = (unsigned short*)p; p += (size_t)nrows * HID * 2;
  unsigned short* Zb  = (unsigned short*)p; p += (size_t)nrows * HID * 2;
  unsigned short* W1P = (unsigned short*)p; p += (size_t)LAT * HID * 2;
  unsigned short* W2T = (unsigned short*)p; p += (size_t)HID * HID * 2;
  float* pS = (float*)p;  p += (size_t)nbb * HID * 4;
  float* pQ = (float*)p;  p += (size_t)nbb * HID * 4;
  float* nrmAll = (float*)p; p += (size_t)nrows * 4;
  float* n1v = nrmAll;
  float* n2v = nrmAll + nx;
  unsigned short* Z1b = Zb;
  unsigned short* Z2b = Zb + (size_t)nx * HID;

  const int xblocks = (nrows * LAT) / 2048;  // 2560
  k_prep<<<20 + xblocks, 256, 0, stream>>>(w1, w2, variations, exemplar, nx,
                                           W1P, W2T, XbP);
  k_gemm1<<<nbb, 256, 0, stream>>>(XbP, W1P, Hb, pS, pQ);
  k_gemm2<<<nbb, 256, 0, stream>>>(Hb, W2T, pS, pQ, gamma, beta, Zb, nrmAll,
                                   nb1, nbb, (float)nx, (float)ny);
  const int ntx = ny / 128;                  // 16
  const int nwg = (nx / 128) * ntx;          // 1024
  k_dist<<<nwg, 256, 0, stream>>>(Z1b, Z2b, n1v, n2v, D, ny, ntx);
}